// Round 1
// baseline (1096.196 us; speedup 1.0000x reference)
//
#include <hip/hip_runtime.h>
#include <hip/hip_bf16.h>

#define N_NODES 10000
#define N_EDGES 640000
#define D 128

// ---------------------------------------------------------------------------
// Kernel 1: y = x @ W   (f32, vector ALU — no fp32 MFMA on CDNA4)
// 256 threads/block, 32 rows/block. W (64KB) + x-tile (16KB) staged in LDS.
// Wave lanes share the same row -> sx reads are broadcasts (conflict-free);
// sW reads are stride-1 across lanes (conflict-free).
// ---------------------------------------------------------------------------
__global__ __launch_bounds__(256) void gemm_xw(const float* __restrict__ x,
                                               const float* __restrict__ W,
                                               float* __restrict__ y) {
    __shared__ float sW[128 * 128];   // 64 KB
    __shared__ float sx[32 * 128];    // 16 KB
    const int row0 = blockIdx.x * 32;

    // stage W
    for (int i = threadIdx.x; i < 128 * 128 / 4; i += 256)
        ((float4*)sW)[i] = ((const float4*)W)[i];
    // stage 32 rows of x
    for (int i = threadIdx.x; i < 32 * 128 / 4; i += 256) {
        int r = row0 + (i >> 5);
        float4 v = make_float4(0.f, 0.f, 0.f, 0.f);
        if (r < N_NODES) v = ((const float4*)x)[(size_t)r * 32 + (i & 31)];
        ((float4*)sx)[i] = v;
    }
    __syncthreads();

    const int j  = threadIdx.x & 127;   // output column
    const int rg = threadIdx.x >> 7;    // 0..1 (row group)

    float acc[16];
#pragma unroll
    for (int i = 0; i < 16; ++i) acc[i] = 0.f;

    for (int k = 0; k < 128; ++k) {
        float wk = sW[k * 128 + j];
#pragma unroll
        for (int i = 0; i < 16; ++i)
            acc[i] += sx[(rg * 16 + i) * 128 + k] * wk;
    }

#pragma unroll
    for (int i = 0; i < 16; ++i) {
        int r = row0 + rg * 16 + i;
        if (r < N_NODES) y[(size_t)r * 128 + j] = acc[i];
    }
}

// ---------------------------------------------------------------------------
// Kernel 2: out[n][d] = bias[d]  (float4; must run before scatter — the
// harness poisons d_out and never re-poisons, so we own initialization)
// ---------------------------------------------------------------------------
__global__ void init_out(const float* __restrict__ bias, float* __restrict__ out) {
    int i = blockIdx.x * blockDim.x + threadIdx.x;   // float4 index
    if (i < N_NODES * 32)
        ((float4*)out)[i] = ((const float4*)bias)[i & 31];
}

// ---------------------------------------------------------------------------
// Kernel 3: for each edge e: out[dst[e]][:] += w[e] * y[src[e]][:]
// 32 lanes per edge, float4 gather, 4 scalar f32 atomicAdds per lane.
// ---------------------------------------------------------------------------
__global__ void scatter_edges(const float* __restrict__ y,
                              const int* __restrict__ src,
                              const int* __restrict__ dst,
                              const float* __restrict__ w,
                              float* __restrict__ out) {
    long long t = (long long)blockIdx.x * blockDim.x + threadIdx.x;
    int e = (int)(t >> 5);
    int c = (int)(t & 31);
    if (e >= N_EDGES) return;

    float we = w[e];
    int s = src[e];
    int d = dst[e];

    float4 v = ((const float4*)(y + (size_t)s * D))[c];
    float* o = out + (size_t)d * D + c * 4;
    atomicAdd(o + 0, we * v.x);
    atomicAdd(o + 1, we * v.y);
    atomicAdd(o + 2, we * v.z);
    atomicAdd(o + 3, we * v.w);
}

extern "C" void kernel_launch(void* const* d_in, const int* in_sizes, int n_in,
                              void* d_out, int out_size, void* d_ws, size_t ws_size,
                              hipStream_t stream) {
    const float* x    = (const float*)d_in[0];
    const int*   src  = (const int*)d_in[1];
    const int*   dst  = (const int*)d_in[2];
    const float* w    = (const float*)d_in[3];
    const float* W    = (const float*)d_in[4];
    const float* bias = (const float*)d_in[5];
    float* out = (float*)d_out;

    float* y = (float*)d_ws;   // 10000*128*4 = 5.12 MB scratch

    // 1) y = x @ W
    gemm_xw<<<(N_NODES + 31) / 32, 256, 0, stream>>>(x, W, y);

    // 2) out = bias (broadcast)
    init_out<<<(N_NODES * 32 + 255) / 256, 256, 0, stream>>>(bias, out);

    // 3) scatter-add edges
    long long total = (long long)N_EDGES * 32;
    int blocks = (int)((total + 255) / 256);
    scatter_edges<<<blocks, 256, 0, stream>>>(y, src, dst, w, out);
}

// Round 2
// 170.044 us; speedup vs baseline: 6.4465x; 6.4465x over previous
//
#include <hip/hip_runtime.h>
#include <hip/hip_bf16.h>

#define N_NODES 10000
#define N_EDGES 640000
#define D 128

// ---------------------------------------------------------------------------
// Kernel 1: y = x @ W   (f32 vector ALU — no fp32 MFMA on CDNA4)
// ---------------------------------------------------------------------------
__global__ __launch_bounds__(256) void gemm_xw(const float* __restrict__ x,
                                               const float* __restrict__ W,
                                               float* __restrict__ y) {
    __shared__ float sW[128 * 128];   // 64 KB
    __shared__ float sx[32 * 128];    // 16 KB
    const int row0 = blockIdx.x * 32;

    for (int i = threadIdx.x; i < 128 * 128 / 4; i += 256)
        ((float4*)sW)[i] = ((const float4*)W)[i];
    for (int i = threadIdx.x; i < 32 * 128 / 4; i += 256) {
        int r = row0 + (i >> 5);
        float4 v = make_float4(0.f, 0.f, 0.f, 0.f);
        if (r < N_NODES) v = ((const float4*)x)[(size_t)r * 32 + (i & 31)];
        ((float4*)sx)[i] = v;
    }
    __syncthreads();

    const int j  = threadIdx.x & 127;
    const int rg = threadIdx.x >> 7;

    float acc[16];
#pragma unroll
    for (int i = 0; i < 16; ++i) acc[i] = 0.f;

    for (int k = 0; k < 128; ++k) {
        float wk = sW[k * 128 + j];
#pragma unroll
        for (int i = 0; i < 16; ++i)
            acc[i] += sx[(rg * 16 + i) * 128 + k] * wk;
    }

#pragma unroll
    for (int i = 0; i < 16; ++i) {
        int r = row0 + rg * 16 + i;
        if (r < N_NODES) y[(size_t)r * 128 + j] = acc[i];
    }
}

// ---------------------------------------------------------------------------
// Kernel 2: histogram of dst  (cnt must be zeroed first via hipMemsetAsync)
// ---------------------------------------------------------------------------
__global__ void hist_dst(const int* __restrict__ dst, int* __restrict__ cnt) {
    int e = blockIdx.x * blockDim.x + threadIdx.x;
    if (e < N_EDGES) atomicAdd(&cnt[dst[e]], 1);
}

// ---------------------------------------------------------------------------
// Kernel 3: single-block exclusive scan of 10000 counts -> offs[10001],
// and copy to cursor[] for the fill kernel.
// ---------------------------------------------------------------------------
__global__ __launch_bounds__(1024) void scan_offsets(const int* __restrict__ cnt,
                                                     int* __restrict__ offs,
                                                     int* __restrict__ cursor) {
    __shared__ int part[1024];
    const int t = threadIdx.x;
    const int base = t * 10;

    int local[10];
    int s = 0;
#pragma unroll
    for (int i = 0; i < 10; ++i) {
        int v = (base + i < N_NODES) ? cnt[base + i] : 0;
        local[i] = s;
        s += v;
    }
    part[t] = s;
    __syncthreads();

    // Hillis-Steele inclusive scan over 1024 partials
    for (int off = 1; off < 1024; off <<= 1) {
        int v = (t >= off) ? part[t - off] : 0;
        __syncthreads();
        part[t] += v;
        __syncthreads();
    }

    int pre = (t == 0) ? 0 : part[t - 1];
#pragma unroll
    for (int i = 0; i < 10; ++i) {
        if (base + i < N_NODES) {
            int o = pre + local[i];
            offs[base + i]   = o;
            cursor[base + i] = o;
        }
    }
    if (t == 1023) offs[N_NODES] = part[1023];
}

// ---------------------------------------------------------------------------
// Kernel 4: fill CSR edge-id list (order within a node is arbitrary)
// ---------------------------------------------------------------------------
__global__ void fill_csr(const int* __restrict__ dst, int* __restrict__ cursor,
                         int* __restrict__ eid) {
    int e = blockIdx.x * blockDim.x + threadIdx.x;
    if (e < N_EDGES) {
        int pos = atomicAdd(&cursor[dst[e]], 1);
        eid[pos] = e;
    }
}

// ---------------------------------------------------------------------------
// Kernel 5: one wave per node: out[n] = sum_e w[e] * y[src[e]] + bias
// lanes 0-31 handle even edge slots, lanes 32-63 odd slots; each lane owns
// a float4 column chunk (c = lane&31). 2-deep unroll for memory-level ||ism.
// ---------------------------------------------------------------------------
__global__ __launch_bounds__(256) void gather_nodes(const float* __restrict__ y,
                                                    const int* __restrict__ src,
                                                    const float* __restrict__ w,
                                                    const int* __restrict__ offs,
                                                    const int* __restrict__ eid,
                                                    const float* __restrict__ bias,
                                                    float* __restrict__ out) {
    const int n = blockIdx.x * 4 + (threadIdx.x >> 6);
    if (n >= N_NODES) return;
    const int lane = threadIdx.x & 63;
    const int c    = lane & 31;
    const int half = lane >> 5;

    const int beg = offs[n];
    const int end = offs[n + 1];

    float4 acc = make_float4(0.f, 0.f, 0.f, 0.f);

    int i = beg + half;
    // 2-deep unrolled main loop (per half-wave stride is 2)
    for (; i + 2 < end; i += 4) {
        int e0 = eid[i];
        int e1 = eid[i + 2];
        int s0 = src[e0];
        int s1 = src[e1];
        float w0 = w[e0];
        float w1 = w[e1];
        float4 v0 = ((const float4*)(y + (size_t)s0 * D))[c];
        float4 v1 = ((const float4*)(y + (size_t)s1 * D))[c];
        acc.x += w0 * v0.x; acc.y += w0 * v0.y; acc.z += w0 * v0.z; acc.w += w0 * v0.w;
        acc.x += w1 * v1.x; acc.y += w1 * v1.y; acc.z += w1 * v1.z; acc.w += w1 * v1.w;
    }
    for (; i < end; i += 2) {
        int e0 = eid[i];
        int s0 = src[e0];
        float w0 = w[e0];
        float4 v0 = ((const float4*)(y + (size_t)s0 * D))[c];
        acc.x += w0 * v0.x; acc.y += w0 * v0.y; acc.z += w0 * v0.z; acc.w += w0 * v0.w;
    }

    // combine the two halves
    acc.x += __shfl_xor(acc.x, 32, 64);
    acc.y += __shfl_xor(acc.y, 32, 64);
    acc.z += __shfl_xor(acc.z, 32, 64);
    acc.w += __shfl_xor(acc.w, 32, 64);

    if (half == 0) {
        float4 b = ((const float4*)bias)[c];
        float4 r = make_float4(acc.x + b.x, acc.y + b.y, acc.z + b.z, acc.w + b.w);
        ((float4*)(out + (size_t)n * D))[c] = r;
    }
}

extern "C" void kernel_launch(void* const* d_in, const int* in_sizes, int n_in,
                              void* d_out, int out_size, void* d_ws, size_t ws_size,
                              hipStream_t stream) {
    const float* x    = (const float*)d_in[0];
    const int*   src  = (const int*)d_in[1];
    const int*   dst  = (const int*)d_in[2];
    const float* w    = (const float*)d_in[3];
    const float* W    = (const float*)d_in[4];
    const float* bias = (const float*)d_in[5];
    float* out = (float*)d_out;

    // workspace layout (256B aligned slabs)
    char* ws = (char*)d_ws;
    float* y      = (float*)(ws);                       // 5,120,000 B
    int*   cnt    = (int*)  (ws + 5120000);             //    40,960 B (10001 ints)
    int*   offs   = (int*)  (ws + 5120000 + 40960);     //    40,960 B
    int*   cursor = (int*)  (ws + 5120000 + 2*40960);   //    40,960 B
    int*   eid    = (int*)  (ws + 5120000 + 3*40960);   // 2,560,000 B
    // total ~7.8 MB

    // 1) y = x @ W
    gemm_xw<<<(N_NODES + 31) / 32, 256, 0, stream>>>(x, W, y);

    // 2) CSR build: histogram -> scan -> fill
    hipMemsetAsync(cnt, 0, (N_NODES + 1) * sizeof(int), stream);
    hist_dst<<<(N_EDGES + 255) / 256, 256, 0, stream>>>(dst, cnt);
    scan_offsets<<<1, 1024, 0, stream>>>(cnt, offs, cursor);
    fill_csr<<<(N_EDGES + 255) / 256, 256, 0, stream>>>(dst, cursor, eid);

    // 3) gather-reduce per node (+bias)
    gather_nodes<<<(N_NODES + 3) / 4, 256, 0, stream>>>(y, src, w, offs, eid, bias, out);
}

// Round 3
// 125.277 us; speedup vs baseline: 8.7502x; 1.3573x over previous
//
#include <hip/hip_runtime.h>
#include <hip/hip_bf16.h>

#define N_NODES 10000
#define N_EDGES 640000
#define D 128

#define GEMM_BLOCKS 313   // ceil(10000/32)
#define HIST_BLOCKS 256

__device__ __forceinline__ unsigned short f2bf(float f) {
    unsigned int u = __float_as_uint(f);
    unsigned int r = (u + 0x7fffu + ((u >> 16) & 1u)) >> 16;  // RNE
    return (unsigned short)r;
}

// ---------------------------------------------------------------------------
// Kernel 1 (fused): blocks [0,GEMM_BLOCKS) compute y = bf16(x @ W);
// blocks [GEMM_BLOCKS, +HIST_BLOCKS) histogram dst into cnt (concurrent,
// independent work — saves a launch and hides hist under the GEMM).
// GEMM: 256 threads = 32 cols-quads x 8 row-quads; per 4-k-chunk:
// 8x ds_read_b128 + 64 FMA (VALU-bound, ~2x fewer LDS ops than R2).
// ---------------------------------------------------------------------------
__global__ __launch_bounds__(256) void gemm_hist(const float* __restrict__ x,
                                                 const float* __restrict__ W,
                                                 const int* __restrict__ dst,
                                                 unsigned short* __restrict__ y,
                                                 int* __restrict__ cnt) {
    if (blockIdx.x >= GEMM_BLOCKS) {
        int b = blockIdx.x - GEMM_BLOCKS;
        for (int e = b * 256 + threadIdx.x; e < N_EDGES; e += HIST_BLOCKS * 256)
            atomicAdd(&cnt[dst[e]], 1);
        return;
    }

    __shared__ float sW[128 * 128];   // 64 KB
    __shared__ float sx[32 * 128];    // 16 KB
    const int row0 = blockIdx.x * 32;

    for (int i = threadIdx.x; i < 128 * 128 / 4; i += 256)
        ((float4*)sW)[i] = ((const float4*)W)[i];
    for (int i = threadIdx.x; i < 32 * 128 / 4; i += 256) {
        int r = row0 + (i >> 5);
        float4 v = make_float4(0.f, 0.f, 0.f, 0.f);
        if (r < N_NODES) v = ((const float4*)x)[(size_t)r * 32 + (i & 31)];
        ((float4*)sx)[i] = v;
    }
    __syncthreads();

    const int colq = threadIdx.x & 31;   // cols colq*4 .. +3
    const int rowq = threadIdx.x >> 5;   // rows rowq*4 .. +3

    float acc[4][4];
#pragma unroll
    for (int r = 0; r < 4; ++r)
#pragma unroll
        for (int j = 0; j < 4; ++j) acc[r][j] = 0.f;

    for (int k = 0; k < 128; k += 4) {
        float4 wk0 = *(const float4*)&sW[(k + 0) * 128 + colq * 4];
        float4 wk1 = *(const float4*)&sW[(k + 1) * 128 + colq * 4];
        float4 wk2 = *(const float4*)&sW[(k + 2) * 128 + colq * 4];
        float4 wk3 = *(const float4*)&sW[(k + 3) * 128 + colq * 4];
#pragma unroll
        for (int r = 0; r < 4; ++r) {
            float4 xv = *(const float4*)&sx[(rowq * 4 + r) * 128 + k];
            acc[r][0] += xv.x * wk0.x + xv.y * wk1.x + xv.z * wk2.x + xv.w * wk3.x;
            acc[r][1] += xv.x * wk0.y + xv.y * wk1.y + xv.z * wk2.y + xv.w * wk3.y;
            acc[r][2] += xv.x * wk0.z + xv.y * wk1.z + xv.z * wk2.z + xv.w * wk3.z;
            acc[r][3] += xv.x * wk0.w + xv.y * wk1.w + xv.z * wk2.w + xv.w * wk3.w;
        }
    }

#pragma unroll
    for (int r = 0; r < 4; ++r) {
        int row = row0 + rowq * 4 + r;
        if (row < N_NODES) {
            ushort4 o;
            o.x = f2bf(acc[r][0]);
            o.y = f2bf(acc[r][1]);
            o.z = f2bf(acc[r][2]);
            o.w = f2bf(acc[r][3]);
            *(ushort4*)&y[(size_t)row * D + colq * 4] = o;
        }
    }
}

// ---------------------------------------------------------------------------
// Kernel 2: single-block exclusive scan of counts -> offs[10001] + cursor copy
// ---------------------------------------------------------------------------
__global__ __launch_bounds__(1024) void scan_offsets(const int* __restrict__ cnt,
                                                     int* __restrict__ offs,
                                                     int* __restrict__ cursor) {
    __shared__ int part[1024];
    const int t = threadIdx.x;
    const int base = t * 10;

    int local[10];
    int s = 0;
#pragma unroll
    for (int i = 0; i < 10; ++i) {
        int v = (base + i < N_NODES) ? cnt[base + i] : 0;
        local[i] = s;
        s += v;
    }
    part[t] = s;
    __syncthreads();

    for (int off = 1; off < 1024; off <<= 1) {
        int v = (t >= off) ? part[t - off] : 0;
        __syncthreads();
        part[t] += v;
        __syncthreads();
    }

    int pre = (t == 0) ? 0 : part[t - 1];
#pragma unroll
    for (int i = 0; i < 10; ++i) {
        if (base + i < N_NODES) {
            int o = pre + local[i];
            offs[base + i]   = o;
            cursor[base + i] = o;
        }
    }
    if (t == 1023) offs[N_NODES] = part[1023];
}

// ---------------------------------------------------------------------------
// Kernel 3: fill CSR with PACKED values (src, w) — removes the eid->src/w
// double indirection from the gather's critical path.
// ---------------------------------------------------------------------------
__global__ void fill_csr(const int* __restrict__ src, const int* __restrict__ dst,
                         const float* __restrict__ w, int* __restrict__ cursor,
                         int* __restrict__ sv, float* __restrict__ wv) {
    int e = blockIdx.x * blockDim.x + threadIdx.x;
    if (e < N_EDGES) {
        int pos = atomicAdd(&cursor[dst[e]], 1);
        sv[pos] = src[e];
        wv[pos] = w[e];
    }
}

// ---------------------------------------------------------------------------
// Kernel 4: one wave per node: out[n] = sum w[e]*y_bf16[src[e]] + bias.
// 4 groups of 16 lanes; group g walks slots (beg+g, stride 4); lane owns
// 8 bf16 columns (16B uint4 load). 2-deep unroll for MLP. Cross-group
// reduce via 2 shfl_xor, lanes 0-15 write the f32 row (512 B coalesced).
// ---------------------------------------------------------------------------
__global__ __launch_bounds__(256) void gather_nodes(const unsigned short* __restrict__ y,
                                                    const int* __restrict__ offs,
                                                    const int* __restrict__ sv,
                                                    const float* __restrict__ wv,
                                                    const float* __restrict__ bias,
                                                    float* __restrict__ out) {
    const int n = blockIdx.x * 4 + (threadIdx.x >> 6);
    if (n >= N_NODES) return;
    const int lane = threadIdx.x & 63;
    const int c    = lane & 15;   // owns cols c*8 .. c*8+7
    const int g    = lane >> 4;   // group 0..3

    const int beg = offs[n];
    const int end = offs[n + 1];

    float acc[8];
#pragma unroll
    for (int j = 0; j < 8; ++j) acc[j] = 0.f;

    int i = beg + g;
    for (; i + 4 < end; i += 8) {
        int   s0 = sv[i];
        int   s1 = sv[i + 4];
        float w0 = wv[i];
        float w1 = wv[i + 4];
        uint4 u0 = *(const uint4*)(y + (size_t)s0 * D + c * 8);
        uint4 u1 = *(const uint4*)(y + (size_t)s1 * D + c * 8);
        const unsigned int* p0 = (const unsigned int*)&u0;
        const unsigned int* p1 = (const unsigned int*)&u1;
#pragma unroll
        for (int q = 0; q < 4; ++q) {
            acc[2 * q]     += w0 * __uint_as_float(p0[q] << 16);
            acc[2 * q + 1] += w0 * __uint_as_float(p0[q] & 0xffff0000u);
        }
#pragma unroll
        for (int q = 0; q < 4; ++q) {
            acc[2 * q]     += w1 * __uint_as_float(p1[q] << 16);
            acc[2 * q + 1] += w1 * __uint_as_float(p1[q] & 0xffff0000u);
        }
    }
    for (; i < end; i += 4) {
        int   s0 = sv[i];
        float w0 = wv[i];
        uint4 u0 = *(const uint4*)(y + (size_t)s0 * D + c * 8);
        const unsigned int* p0 = (const unsigned int*)&u0;
#pragma unroll
        for (int q = 0; q < 4; ++q) {
            acc[2 * q]     += w0 * __uint_as_float(p0[q] << 16);
            acc[2 * q + 1] += w0 * __uint_as_float(p0[q] & 0xffff0000u);
        }
    }

#pragma unroll
    for (int j = 0; j < 8; ++j) {
        acc[j] += __shfl_xor(acc[j], 16, 64);
        acc[j] += __shfl_xor(acc[j], 32, 64);
    }

    if (g == 0) {
        float4 b0 = *(const float4*)&bias[c * 8];
        float4 b1 = *(const float4*)&bias[c * 8 + 4];
        float4 r0 = make_float4(acc[0] + b0.x, acc[1] + b0.y, acc[2] + b0.z, acc[3] + b0.w);
        float4 r1 = make_float4(acc[4] + b1.x, acc[5] + b1.y, acc[6] + b1.z, acc[7] + b1.w);
        *(float4*)&out[(size_t)n * D + c * 8]     = r0;
        *(float4*)&out[(size_t)n * D + c * 8 + 4] = r1;
    }
}

extern "C" void kernel_launch(void* const* d_in, const int* in_sizes, int n_in,
                              void* d_out, int out_size, void* d_ws, size_t ws_size,
                              hipStream_t stream) {
    const float* x    = (const float*)d_in[0];
    const int*   src  = (const int*)d_in[1];
    const int*   dst  = (const int*)d_in[2];
    const float* w    = (const float*)d_in[3];
    const float* W    = (const float*)d_in[4];
    const float* bias = (const float*)d_in[5];
    float* out = (float*)d_out;

    // workspace layout (256B-aligned slabs), total ~7.8 MB
    char* ws = (char*)d_ws;
    unsigned short* y      = (unsigned short*)(ws);          // 2,560,000 B (bf16)
    int*            cnt    = (int*)(ws + 2560000);           //    40,960 B
    int*            offs   = (int*)(ws + 2600960);           //    40,960 B
    int*            cursor = (int*)(ws + 2641920);           //    40,960 B
    int*            sv     = (int*)(ws + 2682880);           // 2,560,000 B
    float*          wv     = (float*)(ws + 5242880);         // 2,560,000 B

    hipMemsetAsync(cnt, 0, N_NODES * sizeof(int), stream);

    // 1) y = bf16(x @ W)  ||  histogram(dst)
    gemm_hist<<<GEMM_BLOCKS + HIST_BLOCKS, 256, 0, stream>>>(x, W, dst, y, cnt);

    // 2) scan -> offsets
    scan_offsets<<<1, 1024, 0, stream>>>(cnt, offs, cursor);

    // 3) fill packed CSR values
    fill_csr<<<(N_EDGES + 255) / 256, 256, 0, stream>>>(src, dst, w, cursor, sv, wv);

    // 4) gather-reduce per node (+bias)
    gather_nodes<<<(N_NODES + 3) / 4, 256, 0, stream>>>(y, offs, sv, wv, bias, out);
}

// Round 4
// 103.340 us; speedup vs baseline: 10.6077x; 1.2123x over previous
//
#include <hip/hip_runtime.h>
#include <hip/hip_bf16.h>

#define N_NODES 10000
#define N_EDGES 640000
#define D 128

#define GEMM_BLOCKS 313        // ceil(10000/32)
#define BH 40                  // hist/fill blocks
#define CHUNK (N_EDGES / BH)   // 16000 edges per block
#define PSTRIDE 10016          // padded stride for cnt_part rows

__device__ __forceinline__ unsigned short f2bf(float f) {
    unsigned int u = __float_as_uint(f);
    unsigned int r = (u + 0x7fffu + ((u >> 16) & 1u)) >> 16;  // RNE
    return (unsigned short)r;
}

// ---------------------------------------------------------------------------
// Kernel 1 (fused): blocks [0,GEMM_BLOCKS) compute y = bf16(x @ W);
// blocks [GEMM_BLOCKS, +BH) build per-block LDS histograms of dst and write
// partial counts cnt_part[b][n] NON-atomically (no global atomics anywhere).
// ---------------------------------------------------------------------------
__global__ __launch_bounds__(256) void gemm_hist(const float* __restrict__ x,
                                                 const float* __restrict__ W,
                                                 const int* __restrict__ dst,
                                                 unsigned short* __restrict__ y,
                                                 int* __restrict__ cnt_part) {
    __shared__ float sW[128 * 128];   // 64 KB (hist blocks reuse as int hist)
    __shared__ float sx[32 * 128];    // 16 KB

    if (blockIdx.x >= GEMM_BLOCKS) {
        // ---- histogram block ----
        int b = blockIdx.x - GEMM_BLOCKS;
        int* h = (int*)sW;            // 10000 ints = 40 KB
        for (int i = threadIdx.x; i < N_NODES; i += 256) h[i] = 0;
        __syncthreads();
        const int e0 = b * CHUNK;
        for (int i = threadIdx.x; i < CHUNK; i += 256)
            atomicAdd(&h[dst[e0 + i]], 1);          // LDS atomic (on-CU)
        __syncthreads();
        for (int i = threadIdx.x; i < N_NODES; i += 256)
            cnt_part[b * PSTRIDE + i] = h[i];       // coalesced, non-atomic
        return;
    }

    // ---- GEMM block ----
    const int row0 = blockIdx.x * 32;

    for (int i = threadIdx.x; i < 128 * 128 / 4; i += 256)
        ((float4*)sW)[i] = ((const float4*)W)[i];
    for (int i = threadIdx.x; i < 32 * 128 / 4; i += 256) {
        int r = row0 + (i >> 5);
        float4 v = make_float4(0.f, 0.f, 0.f, 0.f);
        if (r < N_NODES) v = ((const float4*)x)[(size_t)r * 32 + (i & 31)];
        ((float4*)sx)[i] = v;
    }
    __syncthreads();

    const int colq = threadIdx.x & 31;   // cols colq*4 .. +3
    const int rowq = threadIdx.x >> 5;   // rows rowq*4 .. +3

    float acc[4][4];
#pragma unroll
    for (int r = 0; r < 4; ++r)
#pragma unroll
        for (int j = 0; j < 4; ++j) acc[r][j] = 0.f;

    for (int k = 0; k < 128; k += 4) {
        float4 wk0 = *(const float4*)&sW[(k + 0) * 128 + colq * 4];
        float4 wk1 = *(const float4*)&sW[(k + 1) * 128 + colq * 4];
        float4 wk2 = *(const float4*)&sW[(k + 2) * 128 + colq * 4];
        float4 wk3 = *(const float4*)&sW[(k + 3) * 128 + colq * 4];
#pragma unroll
        for (int r = 0; r < 4; ++r) {
            float4 xv = *(const float4*)&sx[(rowq * 4 + r) * 128 + k];
            acc[r][0] += xv.x * wk0.x + xv.y * wk1.x + xv.z * wk2.x + xv.w * wk3.x;
            acc[r][1] += xv.x * wk0.y + xv.y * wk1.y + xv.z * wk2.y + xv.w * wk3.y;
            acc[r][2] += xv.x * wk0.z + xv.y * wk1.z + xv.z * wk2.z + xv.w * wk3.z;
            acc[r][3] += xv.x * wk0.w + xv.y * wk1.w + xv.z * wk2.w + xv.w * wk3.w;
        }
    }

#pragma unroll
    for (int r = 0; r < 4; ++r) {
        int row = row0 + rowq * 4 + r;
        if (row < N_NODES) {
            ushort4 o;
            o.x = f2bf(acc[r][0]);
            o.y = f2bf(acc[r][1]);
            o.z = f2bf(acc[r][2]);
            o.w = f2bf(acc[r][3]);
            *(ushort4*)&y[(size_t)row * D + colq * 4] = o;
        }
    }
}

// ---------------------------------------------------------------------------
// Kernel 2: per node n: exclusive prefix over the 40 block-partials (in
// place) and total count cnt[n]. Reads/writes coalesced across lanes.
// ---------------------------------------------------------------------------
__global__ void reduce_prefix(int* __restrict__ cnt_part, int* __restrict__ cnt) {
    int n = blockIdx.x * blockDim.x + threadIdx.x;
    if (n >= N_NODES) return;
    int run = 0;
#pragma unroll 8
    for (int b = 0; b < BH; ++b) {
        int c = cnt_part[b * PSTRIDE + n];
        cnt_part[b * PSTRIDE + n] = run;
        run += c;
    }
    cnt[n] = run;
}

// ---------------------------------------------------------------------------
// Kernel 3: single-block exclusive scan of counts -> offs[10001]
// ---------------------------------------------------------------------------
__global__ __launch_bounds__(1024) void scan_offsets(const int* __restrict__ cnt,
                                                     int* __restrict__ offs) {
    __shared__ int part[1024];
    const int t = threadIdx.x;
    const int base = t * 10;

    int local[10];
    int s = 0;
#pragma unroll
    for (int i = 0; i < 10; ++i) {
        int v = (base + i < N_NODES) ? cnt[base + i] : 0;
        local[i] = s;
        s += v;
    }
    part[t] = s;
    __syncthreads();

    for (int off = 1; off < 1024; off <<= 1) {
        int v = (t >= off) ? part[t - off] : 0;
        __syncthreads();
        part[t] += v;
        __syncthreads();
    }

    int pre = (t == 0) ? 0 : part[t - 1];
#pragma unroll
    for (int i = 0; i < 10; ++i)
        if (base + i < N_NODES) offs[base + i] = pre + local[i];
    if (t == 1023) offs[N_NODES] = part[1023];
}

// ---------------------------------------------------------------------------
// Kernel 4: fill packed CSR values via LDS cursor (no global atomics).
// Block b seeds cursor[n] = offs[n] + cnt_part[b][n], then places its own
// 16000 edges with LDS atomicAdd. One 8B packed write per edge.
// ---------------------------------------------------------------------------
__global__ __launch_bounds__(256) void fill_pack(const int* __restrict__ src,
                                                 const int* __restrict__ dst,
                                                 const float* __restrict__ w,
                                                 const int* __restrict__ offs,
                                                 const int* __restrict__ cnt_part,
                                                 int2* __restrict__ swv) {
    __shared__ int cur[N_NODES];   // 40 KB
    const int b = blockIdx.x;
    for (int i = threadIdx.x; i < N_NODES; i += 256)
        cur[i] = offs[i] + cnt_part[b * PSTRIDE + i];
    __syncthreads();
    const int e0 = b * CHUNK;
    for (int i = threadIdx.x; i < CHUNK; i += 256) {
        int e = e0 + i;
        int pos = atomicAdd(&cur[dst[e]], 1);       // LDS atomic
        swv[pos] = make_int2(src[e], __float_as_int(w[e]));
    }
}

// ---------------------------------------------------------------------------
// Kernel 5: one wave per node: out[n] = sum w*y_bf16[src] + bias.
// 4 groups of 16 lanes; packed int2 per slot (one broadcast load); lane owns
// 8 bf16 cols (16B load). Cross-group reduce via 2 shfl_xor.
// ---------------------------------------------------------------------------
__global__ __launch_bounds__(256) void gather_nodes(const unsigned short* __restrict__ y,
                                                    const int* __restrict__ offs,
                                                    const int2* __restrict__ swv,
                                                    const float* __restrict__ bias,
                                                    float* __restrict__ out) {
    const int n = blockIdx.x * 4 + (threadIdx.x >> 6);
    if (n >= N_NODES) return;
    const int lane = threadIdx.x & 63;
    const int c    = lane & 15;   // cols c*8 .. c*8+7
    const int g    = lane >> 4;   // group 0..3

    const int beg = offs[n];
    const int end = offs[n + 1];

    float acc[8];
#pragma unroll
    for (int j = 0; j < 8; ++j) acc[j] = 0.f;

    int i = beg + g;
    for (; i + 4 < end; i += 8) {
        int2 a0 = swv[i];
        int2 a1 = swv[i + 4];
        float w0 = __int_as_float(a0.y);
        float w1 = __int_as_float(a1.y);
        uint4 u0 = *(const uint4*)(y + (size_t)a0.x * D + c * 8);
        uint4 u1 = *(const uint4*)(y + (size_t)a1.x * D + c * 8);
        const unsigned int* p0 = (const unsigned int*)&u0;
        const unsigned int* p1 = (const unsigned int*)&u1;
#pragma unroll
        for (int q = 0; q < 4; ++q) {
            acc[2 * q]     += w0 * __uint_as_float(p0[q] << 16);
            acc[2 * q + 1] += w0 * __uint_as_float(p0[q] & 0xffff0000u);
        }
#pragma unroll
        for (int q = 0; q < 4; ++q) {
            acc[2 * q]     += w1 * __uint_as_float(p1[q] << 16);
            acc[2 * q + 1] += w1 * __uint_as_float(p1[q] & 0xffff0000u);
        }
    }
    for (; i < end; i += 4) {
        int2 a0 = swv[i];
        float w0 = __int_as_float(a0.y);
        uint4 u0 = *(const uint4*)(y + (size_t)a0.x * D + c * 8);
        const unsigned int* p0 = (const unsigned int*)&u0;
#pragma unroll
        for (int q = 0; q < 4; ++q) {
            acc[2 * q]     += w0 * __uint_as_float(p0[q] << 16);
            acc[2 * q + 1] += w0 * __uint_as_float(p0[q] & 0xffff0000u);
        }
    }

#pragma unroll
    for (int j = 0; j < 8; ++j) {
        acc[j] += __shfl_xor(acc[j], 16, 64);
        acc[j] += __shfl_xor(acc[j], 32, 64);
    }

    if (g == 0) {
        float4 b0 = *(const float4*)&bias[c * 8];
        float4 b1 = *(const float4*)&bias[c * 8 + 4];
        float4 r0 = make_float4(acc[0] + b0.x, acc[1] + b0.y, acc[2] + b0.z, acc[3] + b0.w);
        float4 r1 = make_float4(acc[4] + b1.x, acc[5] + b1.y, acc[6] + b1.z, acc[7] + b1.w);
        *(float4*)&out[(size_t)n * D + c * 8]     = r0;
        *(float4*)&out[(size_t)n * D + c * 8 + 4] = r1;
    }
}

extern "C" void kernel_launch(void* const* d_in, const int* in_sizes, int n_in,
                              void* d_out, int out_size, void* d_ws, size_t ws_size,
                              hipStream_t stream) {
    const float* x    = (const float*)d_in[0];
    const int*   src  = (const int*)d_in[1];
    const int*   dst  = (const int*)d_in[2];
    const float* w    = (const float*)d_in[3];
    const float* W    = (const float*)d_in[4];
    const float* bias = (const float*)d_in[5];
    float* out = (float*)d_out;

    // workspace layout, total ~9.4 MB
    char* ws = (char*)d_ws;
    unsigned short* y        = (unsigned short*)(ws);        // 2,560,000 B (bf16)
    int*            cnt_part = (int*)(ws + 2560000);         // 40*10016*4 = 1,602,560 B
    int*            cnt      = (int*)(ws + 4162560);         //    40,960 B
    int*            offs     = (int*)(ws + 4203520);         //    40,960 B
    int2*           swv      = (int2*)(ws + 4244480);        // 5,120,000 B

    // 1) y = bf16(x @ W)  ||  per-block LDS histograms (no global atomics)
    gemm_hist<<<GEMM_BLOCKS + BH, 256, 0, stream>>>(x, W, dst, y, cnt_part);

    // 2) per-node prefix over block partials (in place) + totals
    reduce_prefix<<<(N_NODES + 255) / 256, 256, 0, stream>>>(cnt_part, cnt);

    // 3) exclusive scan -> offs
    scan_offsets<<<1, 1024, 0, stream>>>(cnt, offs);

    // 4) fill packed CSR values via LDS cursors (no global atomics)
    fill_pack<<<BH, 256, 0, stream>>>(src, dst, w, offs, cnt_part, swv);

    // 5) gather-reduce per node (+bias)
    gather_nodes<<<(N_NODES + 3) / 4, 256, 0, stream>>>(y, offs, swv, bias, out);
}

// Round 5
// 63.390 us; speedup vs baseline: 17.2930x; 1.6302x over previous
//
#include <hip/hip_runtime.h>
#include <hip/hip_bf16.h>

#define N_NODES 10000
#define N_EDGES 640000
#define D 128

#define GEMM_BLOCKS 313        // ceil(10000/32)
#define BH 160                 // hist/fill blocks
#define CHUNK (N_EDGES / BH)   // 4000 edges per block
#define PSTRIDE 10016          // padded stride for cnt_part rows (u16)

__device__ __forceinline__ unsigned short f2bf(float f) {
    unsigned int u = __float_as_uint(f);
    unsigned int r = (u + 0x7fffu + ((u >> 16) & 1u)) >> 16;  // RNE
    return (unsigned short)r;
}

// ---------------------------------------------------------------------------
// Kernel 1: per-block LDS histogram of dst -> u16 partial counts (no global
// atomics). 160 blocks x 4000 edges.
// ---------------------------------------------------------------------------
__global__ __launch_bounds__(256) void hist(const int* __restrict__ dst,
                                            unsigned short* __restrict__ cnt_part) {
    __shared__ int h[N_NODES];   // 40 KB
    for (int i = threadIdx.x; i < N_NODES; i += 256) h[i] = 0;
    __syncthreads();
    const int e0 = blockIdx.x * CHUNK;
    for (int i = threadIdx.x; i < CHUNK; i += 256)
        atomicAdd(&h[dst[e0 + i]], 1);              // LDS atomic (on-CU)
    __syncthreads();
    unsigned short* row = cnt_part + (size_t)blockIdx.x * PSTRIDE;
    for (int i = threadIdx.x; i < N_NODES; i += 256)
        row[i] = (unsigned short)h[i];              // coalesced, non-atomic
}

// ---------------------------------------------------------------------------
// Kernel 2: per node n: exclusive prefix over the 160 block-partials (in
// place, u16) and total count cnt[n].
// ---------------------------------------------------------------------------
__global__ void reduce_prefix(unsigned short* __restrict__ cnt_part,
                              int* __restrict__ cnt) {
    int n = blockIdx.x * blockDim.x + threadIdx.x;
    if (n >= N_NODES) return;
    int run = 0;
#pragma unroll 8
    for (int b = 0; b < BH; ++b) {
        size_t idx = (size_t)b * PSTRIDE + n;
        int c = cnt_part[idx];
        cnt_part[idx] = (unsigned short)run;        // prefix <= degree(n) << 65536
        run += c;
    }
    cnt[n] = run;
}

// ---------------------------------------------------------------------------
// Kernel 3: single-block exclusive scan of counts -> offs[10001]
// ---------------------------------------------------------------------------
__global__ __launch_bounds__(1024) void scan_offsets(const int* __restrict__ cnt,
                                                     int* __restrict__ offs) {
    __shared__ int part[1024];
    const int t = threadIdx.x;
    const int base = t * 10;

    int local[10];
    int s = 0;
#pragma unroll
    for (int i = 0; i < 10; ++i) {
        int v = (base + i < N_NODES) ? cnt[base + i] : 0;
        local[i] = s;
        s += v;
    }
    part[t] = s;
    __syncthreads();

    for (int off = 1; off < 1024; off <<= 1) {
        int v = (t >= off) ? part[t - off] : 0;
        __syncthreads();
        part[t] += v;
        __syncthreads();
    }

    int pre = (t == 0) ? 0 : part[t - 1];
#pragma unroll
    for (int i = 0; i < 10; ++i)
        if (base + i < N_NODES) offs[base + i] = pre + local[i];
    if (t == 1023) offs[N_NODES] = part[1023];
}

// ---------------------------------------------------------------------------
// Kernel 4 (fused): blocks [0,BH) fill the CSR value array via LDS cursors
// (one packed u32 = (src<<16)|bf16(w) per edge); blocks [BH,BH+GEMM_BLOCKS)
// compute y = bf16(x @ W). GEMM hides under the scatter fill.
// ---------------------------------------------------------------------------
__global__ __launch_bounds__(256) void fill_gemm(const float* __restrict__ x,
                                                 const float* __restrict__ W,
                                                 const int* __restrict__ src,
                                                 const int* __restrict__ dst,
                                                 const float* __restrict__ w,
                                                 const int* __restrict__ offs,
                                                 const unsigned short* __restrict__ cnt_part,
                                                 unsigned int* __restrict__ swv,
                                                 unsigned short* __restrict__ y) {
    __shared__ float sW[128 * 128];   // 64 KB (fill blocks reuse as cursors)
    __shared__ float sx[32 * 128];    // 16 KB

    if (blockIdx.x < BH) {
        // ---- fill block ----
        int* cur = (int*)sW;          // 40 KB cursor table
        const int b = blockIdx.x;
        const unsigned short* part = cnt_part + (size_t)b * PSTRIDE;
        for (int i = threadIdx.x; i < N_NODES; i += 256)
            cur[i] = offs[i] + (int)part[i];
        __syncthreads();
        const int e0 = b * CHUNK;
        for (int i = threadIdx.x; i < CHUNK; i += 256) {
            int e = e0 + i;
            int pos = atomicAdd(&cur[dst[e]], 1);   // LDS atomic
            swv[pos] = ((unsigned int)src[e] << 16) | (unsigned int)f2bf(w[e]);
        }
        return;
    }

    // ---- GEMM block ----
    const int row0 = (blockIdx.x - BH) * 32;

    for (int i = threadIdx.x; i < 128 * 128 / 4; i += 256)
        ((float4*)sW)[i] = ((const float4*)W)[i];
    for (int i = threadIdx.x; i < 32 * 128 / 4; i += 256) {
        int r = row0 + (i >> 5);
        float4 v = make_float4(0.f, 0.f, 0.f, 0.f);
        if (r < N_NODES) v = ((const float4*)x)[(size_t)r * 32 + (i & 31)];
        ((float4*)sx)[i] = v;
    }
    __syncthreads();

    const int colq = threadIdx.x & 31;   // cols colq*4 .. +3
    const int rowq = threadIdx.x >> 5;   // rows rowq*4 .. +3

    float acc[4][4];
#pragma unroll
    for (int r = 0; r < 4; ++r)
#pragma unroll
        for (int j = 0; j < 4; ++j) acc[r][j] = 0.f;

    for (int k = 0; k < 128; k += 4) {
        float4 wk0 = *(const float4*)&sW[(k + 0) * 128 + colq * 4];
        float4 wk1 = *(const float4*)&sW[(k + 1) * 128 + colq * 4];
        float4 wk2 = *(const float4*)&sW[(k + 2) * 128 + colq * 4];
        float4 wk3 = *(const float4*)&sW[(k + 3) * 128 + colq * 4];
#pragma unroll
        for (int r = 0; r < 4; ++r) {
            float4 xv = *(const float4*)&sx[(rowq * 4 + r) * 128 + k];
            acc[r][0] += xv.x * wk0.x + xv.y * wk1.x + xv.z * wk2.x + xv.w * wk3.x;
            acc[r][1] += xv.x * wk0.y + xv.y * wk1.y + xv.z * wk2.y + xv.w * wk3.y;
            acc[r][2] += xv.x * wk0.z + xv.y * wk1.z + xv.z * wk2.z + xv.w * wk3.z;
            acc[r][3] += xv.x * wk0.w + xv.y * wk1.w + xv.z * wk2.w + xv.w * wk3.w;
        }
    }

#pragma unroll
    for (int r = 0; r < 4; ++r) {
        int row = row0 + rowq * 4 + r;
        if (row < N_NODES) {
            ushort4 o;
            o.x = f2bf(acc[r][0]);
            o.y = f2bf(acc[r][1]);
            o.z = f2bf(acc[r][2]);
            o.w = f2bf(acc[r][3]);
            *(ushort4*)&y[(size_t)row * D + colq * 4] = o;
        }
    }
}

// ---------------------------------------------------------------------------
// Kernel 5: one wave per node: out[n] = sum w*y_bf16[src] + bias.
// 4 groups of 16 lanes; packed u32 per slot (broadcast load within group);
// lane owns 8 bf16 cols (16B load). Cross-group reduce via 2 shfl_xor.
// ---------------------------------------------------------------------------
__global__ __launch_bounds__(256) void gather_nodes(const unsigned short* __restrict__ y,
                                                    const int* __restrict__ offs,
                                                    const unsigned int* __restrict__ swv,
                                                    const float* __restrict__ bias,
                                                    float* __restrict__ out) {
    const int n = blockIdx.x * 4 + (threadIdx.x >> 6);
    if (n >= N_NODES) return;
    const int lane = threadIdx.x & 63;
    const int c    = lane & 15;   // cols c*8 .. c*8+7
    const int g    = lane >> 4;   // group 0..3

    const int beg = offs[n];
    const int end = offs[n + 1];

    float acc[8];
#pragma unroll
    for (int j = 0; j < 8; ++j) acc[j] = 0.f;

    int i = beg + g;
    for (; i + 4 < end; i += 8) {
        unsigned int a0 = swv[i];
        unsigned int a1 = swv[i + 4];
        float w0 = __uint_as_float(a0 << 16);
        float w1 = __uint_as_float(a1 << 16);
        uint4 u0 = *(const uint4*)(y + (size_t)(a0 >> 16) * D + c * 8);
        uint4 u1 = *(const uint4*)(y + (size_t)(a1 >> 16) * D + c * 8);
        const unsigned int* p0 = (const unsigned int*)&u0;
        const unsigned int* p1 = (const unsigned int*)&u1;
#pragma unroll
        for (int q = 0; q < 4; ++q) {
            acc[2 * q]     += w0 * __uint_as_float(p0[q] << 16);
            acc[2 * q + 1] += w0 * __uint_as_float(p0[q] & 0xffff0000u);
        }
#pragma unroll
        for (int q = 0; q < 4; ++q) {
            acc[2 * q]     += w1 * __uint_as_float(p1[q] << 16);
            acc[2 * q + 1] += w1 * __uint_as_float(p1[q] & 0xffff0000u);
        }
    }
    for (; i < end; i += 4) {
        unsigned int a0 = swv[i];
        float w0 = __uint_as_float(a0 << 16);
        uint4 u0 = *(const uint4*)(y + (size_t)(a0 >> 16) * D + c * 8);
        const unsigned int* p0 = (const unsigned int*)&u0;
#pragma unroll
        for (int q = 0; q < 4; ++q) {
            acc[2 * q]     += w0 * __uint_as_float(p0[q] << 16);
            acc[2 * q + 1] += w0 * __uint_as_float(p0[q] & 0xffff0000u);
        }
    }

#pragma unroll
    for (int j = 0; j < 8; ++j) {
        acc[j] += __shfl_xor(acc[j], 16, 64);
        acc[j] += __shfl_xor(acc[j], 32, 64);
    }

    if (g == 0) {
        float4 b0 = *(const float4*)&bias[c * 8];
        float4 b1 = *(const float4*)&bias[c * 8 + 4];
        float4 r0 = make_float4(acc[0] + b0.x, acc[1] + b0.y, acc[2] + b0.z, acc[3] + b0.w);
        float4 r1 = make_float4(acc[4] + b1.x, acc[5] + b1.y, acc[6] + b1.z, acc[7] + b1.w);
        *(float4*)&out[(size_t)n * D + c * 8]     = r0;
        *(float4*)&out[(size_t)n * D + c * 8 + 4] = r1;
    }
}

extern "C" void kernel_launch(void* const* d_in, const int* in_sizes, int n_in,
                              void* d_out, int out_size, void* d_ws, size_t ws_size,
                              hipStream_t stream) {
    const float* x    = (const float*)d_in[0];
    const int*   src  = (const int*)d_in[1];
    const int*   dst  = (const int*)d_in[2];
    const float* w    = (const float*)d_in[3];
    const float* W    = (const float*)d_in[4];
    const float* bias = (const float*)d_in[5];
    float* out = (float*)d_out;

    // workspace layout, total ~8.4 MB
    char* ws = (char*)d_ws;
    unsigned short* y        = (unsigned short*)(ws);          // 2,560,000 B (bf16)
    unsigned short* cnt_part = (unsigned short*)(ws + 2560000);// 160*10016*2 = 3,205,120 B
    int*            cnt      = (int*)(ws + 5765120);           //    40,960 B
    int*            offs     = (int*)(ws + 5806080);           //    40,960 B
    unsigned int*   swv      = (unsigned int*)(ws + 5847040);  // 2,560,000 B
    // end: 8,407,040 B

    // 1) per-block LDS histograms (no global atomics)
    hist<<<BH, 256, 0, stream>>>(dst, cnt_part);

    // 2) per-node prefix over block partials (in place) + totals
    reduce_prefix<<<(N_NODES + 255) / 256, 256, 0, stream>>>(cnt_part, cnt);

    // 3) exclusive scan -> offs
    scan_offsets<<<1, 1024, 0, stream>>>(cnt, offs);

    // 4) fill packed CSR (LDS cursors)  ||  y = bf16(x @ W)
    fill_gemm<<<BH + GEMM_BLOCKS, 256, 0, stream>>>(x, W, src, dst, w, offs,
                                                    cnt_part, swv, y);

    // 5) gather-reduce per node (+bias)
    gather_nodes<<<(N_NODES + 3) / 4, 256, 0, stream>>>(y, offs, swv, bias, out);
}